// Round 2
// baseline (403.039 us; speedup 1.0000x reference)
//
#include <hip/hip_runtime.h>
#include <stdint.h>

typedef float    f32x16 __attribute__((ext_vector_type(16)));
typedef uint32_t u32x4  __attribute__((ext_vector_type(4)));
typedef uint32_t u32x2  __attribute__((ext_vector_type(2)));
typedef _Float16 half4  __attribute__((ext_vector_type(4)));

#define DEVI static __device__ __forceinline__
#define NB 8
#define NN 2048
#define ND 256

DEVI void gl_lds16(const void* g, void* l) {
  __builtin_amdgcn_global_load_lds(
      (const __attribute__((address_space(1))) void*)g,
      (__attribute__((address_space(3))) void*)l,
      16, 0, 0);
}

// ---------------- prep: adj->bits, inp->fp16, W->W^T fp16 hi/lo ----------------
__global__ __launch_bounds__(256) void k_prep(
    const float* __restrict__ adj, const float* __restrict__ inp,
    const float* __restrict__ W,
    _Float16* __restrict__ xh, _Float16* __restrict__ wth,
    _Float16* __restrict__ wtl, uint32_t* __restrict__ bits)
{
  const int blk = blockIdx.x;
  const int tid = threadIdx.x;
  if (blk < 6144) {
    const long long total = 33554432LL;           // 8*2048*2048
    const long long stride = 6144LL * 256;
    const int lane = tid & 63;
    for (long long g = (long long)blk*256 + tid; g < total; g += stride) {
      float v = adj[g];
      unsigned long long m = __ballot(v != 0.0f);
      if (lane == 0)       bits[g >> 5] = (uint32_t)m;
      else if (lane == 32) bits[g >> 5] = (uint32_t)(m >> 32);
    }
  } else if (blk < 6400) {
    int t = (blk - 6144)*256 + tid;               // 65536 threads, 1048576 float4
    for (int i = t; i < 1048576; i += 65536) {
      float4 v = ((const float4*)inp)[i];
      half4 h = { (_Float16)v.x, (_Float16)v.y, (_Float16)v.z, (_Float16)v.w };
      *(half4*)(xh + (long long)i*4) = h;
    }
  } else {
    int t = (blk - 6400)*256 + tid;               // 16384 threads, 65536 elems
    for (int i = t; i < 65536; i += 16384) {
      int o = i >> 8, k = i & 255;
      float w = W[k*256 + o];
      _Float16 h = (_Float16)w;
      _Float16 l = (_Float16)(w - (float)h);
      wth[i] = h;                                  // i == o*256+k
      wtl[i] = l;
    }
  }
}

// ---------------- hgemm: H = X*W (fp16-split), store H^T bf16 hi/lo permuted ----------------
__global__ __launch_bounds__(256) void k_hgemm(
    const float* __restrict__ x,
    const _Float16* __restrict__ wth, const _Float16* __restrict__ wtl,
    uint16_t* __restrict__ HTh, uint16_t* __restrict__ HTl)
{
  __shared__ __align__(16) _Float16 xs[2][64*256];   // 64KB, swizzled granules
  __shared__ __align__(16) uint16_t bnc[2][4][32*36];

  const int tid = threadIdx.x;
  const int lane = tid & 63;
  const int wv = tid >> 6;
  const int ln31 = lane & 31;
  const int hi = lane >> 5;
  const long long rowg0 = (long long)blockIdx.x * 64;

  // stage + split x tile (64 rows x 256 cols)
  #pragma unroll
  for (int it = 0; it < 16; ++it) {
    int flat = it*256 + tid;
    int r = flat >> 6;
    int c4 = flat & 63;
    float4 v = ((const float4*)x)[rowg0*64 + flat];
    half4 h = { (_Float16)v.x, (_Float16)v.y, (_Float16)v.z, (_Float16)v.w };
    half4 l = { (_Float16)(v.x - (float)h.x), (_Float16)(v.y - (float)h.y),
                (_Float16)(v.z - (float)h.z), (_Float16)(v.w - (float)h.w) };
    int gr = (c4 >> 1) ^ (r & 7);
    int ad = r*256 + gr*8 + (c4 & 1)*4;
    *(half4*)(xs[0] + ad) = h;
    *(half4*)(xs[1] + ad) = l;
  }
  __syncthreads();

  const int rg = wv >> 1;   // row group
  const int og = wv & 1;    // o half
  f32x16 acc[4] = {};
  const int arow = rg*32 + ln31;
  #pragma unroll 2
  for (int ks = 0; ks < 16; ++ks) {
    int slot = (ks*2 + hi) ^ (ln31 & 7);
    u32x4 ah = *(const u32x4*)(xs[0] + arow*256 + slot*8);
    u32x4 al = *(const u32x4*)(xs[1] + arow*256 + slot*8);
    #pragma unroll
    for (int ot = 0; ot < 4; ++ot) {
      int o = og*128 + ot*32 + ln31;
      u32x4 bh = *(const u32x4*)(wth + o*256 + ks*16 + hi*8);
      u32x4 bl = *(const u32x4*)(wtl + o*256 + ks*16 + hi*8);
      asm("v_mfma_f32_32x32x16_f16 %0, %1, %2, %0" : "+v"(acc[ot]) : "v"(ah), "v"(bh));
      asm("v_mfma_f32_32x32x16_f16 %0, %1, %2, %0" : "+v"(acc[ot]) : "v"(al), "v"(bh));
      asm("v_mfma_f32_32x32x16_f16 %0, %1, %2, %0" : "+v"(acc[ot]) : "v"(ah), "v"(bl));
    }
  }
  asm volatile("s_nop 7\n\ts_nop 7\n\ts_nop 7");
  __builtin_amdgcn_sched_barrier(0);

  const int bq  = (int)(rowg0 >> 11);
  const int nl0 = (int)(rowg0 & 2047) + rg*32;
  #pragma unroll 1
  for (int ot = 0; ot < 4; ++ot) {
    uint16_t* bh = bnc[0][wv];
    uint16_t* bl = bnc[1][wv];
    #pragma unroll
    for (int r = 0; r < 16; ++r) {
      float v = acc[ot][r];
      uint32_t t = __float_as_uint(v) + 0x8000u;
      float hf = __uint_as_float(t & 0xFFFF0000u);
      uint32_t t2 = __float_as_uint(v - hf) + 0x8000u;
      int n = (r & 3) + 8*(r >> 2) + 4*hi;
      bh[ln31*36 + n] = (uint16_t)(t  >> 16);
      bl[ln31*36 + n] = (uint16_t)(t2 >> 16);
    }
    __syncthreads();
    // readback transposed + m-permuted (granule order 0,2,1,3), store coalesced
    int orow = lane >> 1, ch = lane & 1;
    const uint16_t* sh = bnc[0][wv] + orow*36 + ch*16;
    const uint16_t* sl = bnc[1][wv] + orow*36 + ch*16;
    u32x2 a0 = *(const u32x2*)(sh + 0);
    u32x2 a1 = *(const u32x2*)(sh + 8);
    u32x2 a2 = *(const u32x2*)(sh + 4);
    u32x2 a3 = *(const u32x2*)(sh + 12);
    u32x4 w0 = { a0.x, a0.y, a1.x, a1.y };
    u32x4 w1 = { a2.x, a2.y, a3.x, a3.y };
    long long off = ((long long)bq*256 + og*128 + ot*32 + orow)*2048 + nl0 + ch*16;
    *(u32x4*)(HTh + off)     = w0;
    *(u32x4*)(HTh + off + 8) = w1;
    u32x2 c0 = *(const u32x2*)(sl + 0);
    u32x2 c1 = *(const u32x2*)(sl + 8);
    u32x2 c2 = *(const u32x2*)(sl + 4);
    u32x2 c3 = *(const u32x2*)(sl + 12);
    u32x4 y0 = { c0.x, c0.y, c1.x, c1.y };
    u32x4 y1 = { c2.x, c2.y, c3.x, c3.y };
    *(u32x4*)(HTl + off)     = y0;
    *(u32x4*)(HTl + off + 8) = y1;
    __syncthreads();
  }
}

// ---------------- fused attention ----------------
template<int MS>
__global__ __launch_bounds__(256, 2) void k_attn(
    const _Float16* __restrict__ xh,
    const uint16_t* __restrict__ HTh, const uint16_t* __restrict__ HTl,
    const uint32_t* __restrict__ bits,
    float* __restrict__ wden, float* __restrict__ wacc,
    const float* __restrict__ bias, float* __restrict__ out)
{
  __shared__ __align__(16) char Ks[16384];   // 32 m-rows x 512B, XOR-swizzled 16B granules
  __shared__ __align__(16) char Hh[20480];   // 256 o-rows x 80B (64B data + 16B pad)
  __shared__ __align__(16) char Hl[20480];
  __shared__ float dls[4][32];

  const int tid  = threadIdx.x;
  const int lane = tid & 63;
  const int wv   = tid >> 6;
  const int hi   = lane >> 5;
  const int ln31 = lane & 31;

  int ms, rb;
  if (MS > 1) { ms = blockIdx.x >> 7; rb = blockIdx.x & 127; }
  else        { ms = 0; rb = blockIdx.x; }
  const int b  = rb >> 4;
  const int n0 = (rb & 15) << 7;
  const int nw = n0 + wv*32;
  const int m_begin = ms * (NN / MS);
  const int npass   = (NN / MS) / 32;

  // Q resident (fp16), B-operand slot j <-> k = ks*16 + hi*8 + j
  const char* qrow = (const char*)xh + ((long long)(b*NN + nw + ln31)) * 512;
  u32x4 q[16];
  #pragma unroll
  for (int ks = 0; ks < 16; ++ks)
    q[ks] = *(const u32x4*)(qrow + ks*32 + hi*16);

  // per-lane staging offsets (pass-invariant)
  int koff[4], hoff[5];
  #pragma unroll
  for (int i = 0; i < 4; ++i) {
    int p = wv*4096 + i*1024 + lane*16;
    int r = p >> 9;
    int gs = (p >> 4) & 31;
    koff[i] = r*512 + ((gs ^ (r & 7)) << 4);
  }
  #pragma unroll
  for (int i = 0; i < 5; ++i) {
    int p = wv*5120 + i*1024 + lane*16;
    int r = p / 80;
    int qq = (p - r*80) >> 4;
    qq = (qq == 4) ? 0 : qq;     // pad granule: harmless duplicate
    hoff[i] = r*4096 + qq*16;
  }
  const char* xb = (const char*)xh  + (long long)b * (NN*512);
  const char* hb = (const char*)HTh + (long long)b * (256*4096);
  const char* lb = (const char*)HTl + (long long)b * (256*4096);
  const uint32_t* brow = bits + (long long)(b*NN + nw + ln31) * 64;

  f32x16 acc[8] = {};
  float den = 0.0f;

  #pragma unroll 1
  for (int ps = 0; ps < npass; ++ps) {
    const int m0 = m_begin + ps*32;
    {
      const char* ksrc = xb + (long long)m0*512;
      #pragma unroll
      for (int i = 0; i < 4; ++i)
        gl_lds16(ksrc + koff[i], Ks + wv*4096 + i*1024);
      const char* hsrc = hb + m0*2;
      const char* lsrc = lb + m0*2;
      #pragma unroll
      for (int i = 0; i < 5; ++i) {
        gl_lds16(hsrc + hoff[i], Hh + wv*5120 + i*1024);
        gl_lds16(lsrc + hoff[i], Hl + wv*5120 + i*1024);
      }
    }
    uint32_t bd = brow[m0 >> 5];
    __syncthreads();

    // S^T = K * Q^T  (fp16 MFMA; C: col=n=lane&31, row=m=(r&3)+8*(r>>2)+4*hi)
    f32x16 s = {};
    #pragma unroll
    for (int ks = 0; ks < 16; ++ks) {
      int slot = (ks*2 + hi) ^ (ln31 & 7);
      u32x4 a = *(const u32x4*)(Ks + ln31*512 + slot*16);
      asm("v_mfma_f32_32x32x16_f16 %0, %1, %2, %0" : "+v"(s) : "v"(a), "v"(q[ks]));
    }
    asm volatile("s_nop 7\n\ts_nop 7\n\ts_nop 7");
    __builtin_amdgcn_sched_barrier(0);

    const uint32_t bd2 = bd >> (hi*4);
    #pragma unroll
    for (int s2 = 0; s2 < 2; ++s2) {
      uint32_t ph[4], pl[4];
      #pragma unroll
      for (int rp = 0; rp < 4; ++rp) {
        uint32_t hw[2], lw[2];
        #pragma unroll
        for (int e = 0; e < 2; ++e) {
          const int r = s2*8 + rp*2 + e;
          float sv = s[r] * 0.09016844005556021f;  // log2(e)/16
          float ex = __builtin_amdgcn_exp2f(sv);
          const int sh = (r & 3) + ((r >> 2) << 3);
          ex = ((bd2 >> sh) & 1u) ? ex : 0.0f;
          den += ex;
          uint32_t t = __float_as_uint(ex) + 0x8000u;
          hw[e] = t >> 16;
          float hf = __uint_as_float(t & 0xFFFF0000u);
          uint32_t t2 = __float_as_uint(ex - hf) + 0x8000u;
          lw[e] = t2 >> 16;
        }
        ph[rp] = hw[0] | (hw[1] << 16);
        pl[rp] = lw[0] | (lw[1] << 16);
      }
      u32x4 pah = { ph[0], ph[1], ph[2], ph[3] };
      u32x4 pal = { pl[0], pl[1], pl[2], pl[3] };
      #pragma unroll
      for (int ot = 0; ot < 8; ++ot) {
        const int ha = (ot*32 + ln31)*80 + s2*32 + hi*16;
        u32x4 vh = *(const u32x4*)(Hh + ha);
        u32x4 vl = *(const u32x4*)(Hl + ha);
        asm("v_mfma_f32_32x32x16_bf16 %0, %1, %2, %0" : "+v"(acc[ot]) : "v"(pah), "v"(vh));
        asm("v_mfma_f32_32x32x16_bf16 %0, %1, %2, %0" : "+v"(acc[ot]) : "v"(pal), "v"(vh));
        asm("v_mfma_f32_32x32x16_bf16 %0, %1, %2, %0" : "+v"(acc[ot]) : "v"(pah), "v"(vl));
      }
    }
    __syncthreads();
  }

  asm volatile("s_nop 7\n\ts_nop 7\n\ts_nop 7");
  __builtin_amdgcn_sched_barrier(0);
  den += __shfl_xor(den, 32);

  if (MS > 1) {
    float* wa = wacc + (((long long)ms*8 + b)*NN + nw)*256;
    #pragma unroll
    for (int ot = 0; ot < 8; ++ot) {
      #pragma unroll
      for (int r = 0; r < 16; ++r) {
        const int n = (r & 3) + 8*(r >> 2) + 4*hi;
        wa[n*256 + ot*32 + ln31] = acc[ot][r];
      }
    }
    if (lane < 32)
      wden[((long long)ms*8 + b)*NN + nw + ln31] = den;
  } else {
    if (lane < 32) dls[wv][ln31] = den;
    __syncthreads();
    #pragma unroll
    for (int ot = 0; ot < 8; ++ot) {
      const float bi = bias[ot*32 + ln31];
      #pragma unroll
      for (int r = 0; r < 16; ++r) {
        const int n = (r & 3) + 8*(r >> 2) + 4*hi;
        const float dn = dls[wv][n] + 1e-10f;
        float v = acc[ot][r] / dn + bi;
        out[((long long)(b*NN + nw + n))*256 + ot*32 + ln31] = (v > 0.0f) ? v : 0.01f*v;
      }
    }
  }
}

// ---------------- combine partials ----------------
template<int MS>
__global__ __launch_bounds__(256) void k_combine(
    const float* __restrict__ wacc, const float* __restrict__ wden,
    const float* __restrict__ bias, float* __restrict__ out)
{
  const int PLANE = 1048576;  // float4 per ms plane
  for (int t = blockIdx.x*256 + threadIdx.x; t < PLANE; t += 2048*256) {
    int row = t >> 6;
    int o4  = t & 63;
    float4 a = ((const float4*)wacc)[t];
    float d = wden[row];
    #pragma unroll
    for (int m = 1; m < MS; ++m) {
      float4 p = ((const float4*)wacc)[t + m*PLANE];
      a.x += p.x; a.y += p.y; a.z += p.z; a.w += p.w;
      d += wden[row + m*16384];
    }
    d += 1e-10f;
    float id = 1.0f / d;
    float4 bi = ((const float4*)bias)[o4];
    float4 r;
    float vx = a.x*id + bi.x; r.x = vx > 0.0f ? vx : 0.01f*vx;
    float vy = a.y*id + bi.y; r.y = vy > 0.0f ? vy : 0.01f*vy;
    float vz = a.z*id + bi.z; r.z = vz > 0.0f ? vz : 0.01f*vz;
    float vw = a.w*id + bi.w; r.w = vw > 0.0f ? vw : 0.01f*vw;
    ((float4*)out)[t] = r;
  }
}

// ---------------- host ----------------
extern "C" void kernel_launch(void* const* d_in, const int* in_sizes, int n_in,
                              void* d_out, int out_size, void* d_ws, size_t ws_size,
                              hipStream_t stream)
{
  const float* inp = (const float*)d_in[0];
  const float* adj = (const float*)d_in[1];
  const float* W   = (const float*)d_in[2];
  const float* bia = (const float*)d_in[3];
  float* out = (float*)d_out;
  char* ws = (char*)d_ws;

  _Float16* xh  = (_Float16*)(ws);                 // 8 MB fp16 x
  uint16_t* HTh = (uint16_t*)(ws + 8388608);       // 8 MB H^T hi
  uint16_t* HTl = (uint16_t*)(ws + 16777216);      // 8 MB H^T lo
  _Float16* wth = (_Float16*)(ws + 25165824);      // 128 KB W^T hi
  _Float16* wtl = (_Float16*)(ws + 25296896);      // 128 KB W^T lo
  uint32_t* bt  = (uint32_t*)(ws + 25427968);      // 4 MB adj bits
  float* den    = (float*)(ws + 29622272);         // 256 KB denom partials
  float* acc    = (float*)(ws + 29884416);         // up to 64 MB acc partials
  const size_t NEED4 = 96993280;
  const size_t NEED2 = 63438848;

  k_prep<<<dim3(6464), dim3(256), 0, stream>>>(adj, inp, W, xh, wth, wtl, bt);
  k_hgemm<<<dim3(256), dim3(256), 0, stream>>>(inp, wth, wtl, HTh, HTl);
  if (ws_size >= NEED4) {
    k_attn<4><<<dim3(512), dim3(256), 0, stream>>>(xh, HTh, HTl, bt, den, acc, nullptr, nullptr);
    k_combine<4><<<dim3(2048), dim3(256), 0, stream>>>(acc, den, bia, out);
  } else if (ws_size >= NEED2) {
    k_attn<2><<<dim3(256), dim3(256), 0, stream>>>(xh, HTh, HTl, bt, den, acc, nullptr, nullptr);
    k_combine<2><<<dim3(2048), dim3(256), 0, stream>>>(acc, den, bia, out);
  } else {
    k_attn<1><<<dim3(128), dim3(256), 0, stream>>>(xh, HTh, HTl, bt, nullptr, nullptr, bia, out);
  }
}

// Round 4
// 379.562 us; speedup vs baseline: 1.0619x; 1.0619x over previous
//
#include <hip/hip_runtime.h>
#include <stdint.h>

typedef float    f32x16 __attribute__((ext_vector_type(16)));
typedef uint32_t u32x4  __attribute__((ext_vector_type(4)));
typedef uint32_t u32x2  __attribute__((ext_vector_type(2)));
typedef _Float16 half4  __attribute__((ext_vector_type(4)));

#define DEVI static __device__ __forceinline__
#define NB 8
#define NN 2048
#define ND 256

DEVI void gl_lds16(const void* g, void* l) {
  __builtin_amdgcn_global_load_lds(
      (const __attribute__((address_space(1))) void*)g,
      (__attribute__((address_space(3))) void*)l,
      16, 0, 0);
}

// ---------------- prep: adj->bits, inp->fp16, W->W^T fp16 hi/lo ----------------
__global__ __launch_bounds__(256) void k_prep(
    const float* __restrict__ adj, const float* __restrict__ inp,
    const float* __restrict__ W,
    _Float16* __restrict__ xh, _Float16* __restrict__ wth,
    _Float16* __restrict__ wtl, uint32_t* __restrict__ bits)
{
  const int blk = blockIdx.x;
  const int tid = threadIdx.x;
  if (blk < 6144) {
    const long long total = 33554432LL;           // 8*2048*2048
    const long long stride = 6144LL * 256;
    const int lane = tid & 63;
    for (long long g = (long long)blk*256 + tid; g < total; g += stride) {
      float v = adj[g];
      unsigned long long m = __ballot(v != 0.0f);
      if (lane == 0)       bits[g >> 5] = (uint32_t)m;
      else if (lane == 32) bits[g >> 5] = (uint32_t)(m >> 32);
    }
  } else if (blk < 6400) {
    int t = (blk - 6144)*256 + tid;               // 65536 threads, 1048576 float4
    for (int i = t; i < 1048576; i += 65536) {
      float4 v = ((const float4*)inp)[i];
      half4 h = { (_Float16)v.x, (_Float16)v.y, (_Float16)v.z, (_Float16)v.w };
      *(half4*)(xh + (long long)i*4) = h;
    }
  } else {
    int t = (blk - 6400)*256 + tid;               // 16384 threads, 65536 elems
    for (int i = t; i < 65536; i += 16384) {
      int o = i >> 8, k = i & 255;
      float w = W[k*256 + o];
      _Float16 h = (_Float16)w;
      _Float16 l = (_Float16)(w - (float)h);
      wth[i] = h;                                  // i == o*256+k
      wtl[i] = l;
    }
  }
}

// ---------------- hgemm: H = X*W (fp16-split), store H^T bf16 hi/lo permuted ----------------
__global__ __launch_bounds__(256) void k_hgemm(
    const float* __restrict__ x,
    const _Float16* __restrict__ wth, const _Float16* __restrict__ wtl,
    uint16_t* __restrict__ HTh, uint16_t* __restrict__ HTl)
{
  __shared__ __align__(16) _Float16 xs[2][64*256];   // 64KB, swizzled granules
  __shared__ __align__(16) uint16_t bnc[2][4][32*36];

  const int tid = threadIdx.x;
  const int lane = tid & 63;
  const int wv = tid >> 6;
  const int ln31 = lane & 31;
  const int hi = lane >> 5;
  const long long rowg0 = (long long)blockIdx.x * 64;

  // stage + split x tile (64 rows x 256 cols)
  #pragma unroll
  for (int it = 0; it < 16; ++it) {
    int flat = it*256 + tid;
    int r = flat >> 6;
    int c4 = flat & 63;
    float4 v = ((const float4*)x)[rowg0*64 + flat];
    half4 h = { (_Float16)v.x, (_Float16)v.y, (_Float16)v.z, (_Float16)v.w };
    half4 l = { (_Float16)(v.x - (float)h.x), (_Float16)(v.y - (float)h.y),
                (_Float16)(v.z - (float)h.z), (_Float16)(v.w - (float)h.w) };
    int gr = (c4 >> 1) ^ (r & 7);
    int ad = r*256 + gr*8 + (c4 & 1)*4;
    *(half4*)(xs[0] + ad) = h;
    *(half4*)(xs[1] + ad) = l;
  }
  __syncthreads();

  const int rg = wv >> 1;   // row group
  const int og = wv & 1;    // o half
  f32x16 acc[4] = {};
  const int arow = rg*32 + ln31;
  #pragma unroll 2
  for (int ks = 0; ks < 16; ++ks) {
    int slot = (ks*2 + hi) ^ (ln31 & 7);
    u32x4 ah = *(const u32x4*)(xs[0] + arow*256 + slot*8);
    u32x4 al = *(const u32x4*)(xs[1] + arow*256 + slot*8);
    #pragma unroll
    for (int ot = 0; ot < 4; ++ot) {
      int o = og*128 + ot*32 + ln31;
      u32x4 bh = *(const u32x4*)(wth + o*256 + ks*16 + hi*8);
      u32x4 bl = *(const u32x4*)(wtl + o*256 + ks*16 + hi*8);
      asm("v_mfma_f32_32x32x16_f16 %0, %1, %2, %0" : "+v"(acc[ot]) : "v"(ah), "v"(bh));
      asm("v_mfma_f32_32x32x16_f16 %0, %1, %2, %0" : "+v"(acc[ot]) : "v"(al), "v"(bh));
      asm("v_mfma_f32_32x32x16_f16 %0, %1, %2, %0" : "+v"(acc[ot]) : "v"(ah), "v"(bl));
    }
  }
  asm volatile("s_nop 7\n\ts_nop 7\n\ts_nop 7");
  __builtin_amdgcn_sched_barrier(0);

  const int bq  = (int)(rowg0 >> 11);
  const int nl0 = (int)(rowg0 & 2047) + rg*32;
  // NOTE: bnc[*][wv] is wave-private -> no __syncthreads needed in this loop;
  // same-wave LDS RAW is ordered by compiler-inserted lgkmcnt waits.
  #pragma unroll 1
  for (int ot = 0; ot < 4; ++ot) {
    uint16_t* bh = bnc[0][wv];
    uint16_t* bl = bnc[1][wv];
    #pragma unroll
    for (int r = 0; r < 16; ++r) {
      float v = acc[ot][r];
      uint32_t t = __float_as_uint(v) + 0x8000u;
      float hf = __uint_as_float(t & 0xFFFF0000u);
      uint32_t t2 = __float_as_uint(v - hf) + 0x8000u;
      int n = (r & 3) + 8*(r >> 2) + 4*hi;
      bh[ln31*36 + n] = (uint16_t)(t  >> 16);
      bl[ln31*36 + n] = (uint16_t)(t2 >> 16);
    }
    // readback transposed + m-permuted (granule order 0,2,1,3), store coalesced
    int orow = lane >> 1, ch = lane & 1;
    const uint16_t* sh = bnc[0][wv] + orow*36 + ch*16;
    const uint16_t* sl = bnc[1][wv] + orow*36 + ch*16;
    u32x2 a0 = *(const u32x2*)(sh + 0);
    u32x2 a1 = *(const u32x2*)(sh + 8);
    u32x2 a2 = *(const u32x2*)(sh + 4);
    u32x2 a3 = *(const u32x2*)(sh + 12);
    u32x4 w0 = { a0.x, a0.y, a1.x, a1.y };
    u32x4 w1 = { a2.x, a2.y, a3.x, a3.y };
    long long off = ((long long)bq*256 + og*128 + ot*32 + orow)*2048 + nl0 + ch*16;
    *(u32x4*)(HTh + off)     = w0;
    *(u32x4*)(HTh + off + 8) = w1;
    u32x2 c0 = *(const u32x2*)(sl + 0);
    u32x2 c1 = *(const u32x2*)(sl + 8);
    u32x2 c2 = *(const u32x2*)(sl + 4);
    u32x2 c3 = *(const u32x2*)(sl + 12);
    u32x4 y0 = { c0.x, c0.y, c1.x, c1.y };
    u32x4 y1 = { c2.x, c2.y, c3.x, c3.y };
    *(u32x4*)(HTl + off)     = y0;
    *(u32x4*)(HTl + off + 8) = y1;
  }
}

// ---------------- fused attention ----------------
template<int MS>
__global__ __launch_bounds__(256, 2) void k_attn(
    const _Float16* __restrict__ xh,
    const uint16_t* __restrict__ HTh, const uint16_t* __restrict__ HTl,
    const uint32_t* __restrict__ bits,
    float* __restrict__ wden, float* __restrict__ wacc,
    const float* __restrict__ bias, float* __restrict__ out)
{
  __shared__ __align__(16) char Ks[16384];   // 32 m-rows x 512B, XOR-swizzled 16B granules
  __shared__ __align__(16) char Hh[20480];   // 256 o-rows x 80B (64B data + 16B pad)
  __shared__ __align__(16) char Hl[20480];
  __shared__ float dls[4][32];

  const int tid  = threadIdx.x;
  const int lane = tid & 63;
  const int wv   = tid >> 6;
  const int hi   = lane >> 5;
  const int ln31 = lane & 31;

  // XCD-grouping decode: all blocks sharing an (ms,b) K/H working set get the
  // same blockIdx%8 -> same XCD -> L2-resident tiles (T1). 4 combos/XCD (MS=4):
  // working set 4 x 768KB = 3MB < 4MB L2.
  int ms, b, n0idx;
  if (MS == 4) {
    int xcd = blockIdx.x & 7, i = blockIdx.x >> 3;   // 512 blocks
    int c = xcd*4 + (i & 3);  ms = c >> 3;  b = c & 7;  n0idx = i >> 2;
  } else if (MS == 2) {
    int xcd = blockIdx.x & 7, i = blockIdx.x >> 3;   // 256 blocks
    int c = xcd*2 + (i & 1);  ms = c >> 3;  b = c & 7;  n0idx = i >> 1;
  } else {
    ms = 0;  b = blockIdx.x & 7;  n0idx = blockIdx.x >> 3;   // 128 blocks
  }
  const int n0 = n0idx << 7;
  const int nw = n0 + wv*32;
  const int m_begin = ms * (NN / MS);
  const int npass   = (NN / MS) / 32;

  // Q resident (fp16), B-operand slot j <-> k = ks*16 + hi*8 + j
  const char* qrow = (const char*)xh + ((long long)(b*NN + nw + ln31)) * 512;
  u32x4 q[16];
  #pragma unroll
  for (int ks = 0; ks < 16; ++ks)
    q[ks] = *(const u32x4*)(qrow + ks*32 + hi*16);

  // per-lane staging offsets (pass-invariant)
  int koff[4], hoff[5];
  #pragma unroll
  for (int i = 0; i < 4; ++i) {
    int p = wv*4096 + i*1024 + lane*16;
    int r = p >> 9;
    int gs = (p >> 4) & 31;
    koff[i] = r*512 + ((gs ^ (r & 7)) << 4);
  }
  #pragma unroll
  for (int i = 0; i < 5; ++i) {
    int p = wv*5120 + i*1024 + lane*16;
    int r = p / 80;
    int qq = (p - r*80) >> 4;
    qq = (qq == 4) ? 0 : qq;     // pad granule: harmless duplicate
    hoff[i] = r*4096 + qq*16;
  }
  const char* xb = (const char*)xh  + (long long)b * (NN*512);
  const char* hb = (const char*)HTh + (long long)b * (256*4096);
  const char* lb = (const char*)HTl + (long long)b * (256*4096);
  const uint32_t* brow = bits + (long long)(b*NN + nw + ln31) * 64;

  f32x16 acc[8] = {};
  float den = 0.0f;
  uint32_t bd_cur = brow[m_begin >> 5];

  #pragma unroll 1
  for (int ps = 0; ps < npass; ++ps) {
    const int m0 = m_begin + ps*32;
    // prefetch next pass's adjacency word (clamped -> always in-bounds)
    const int nwidx = (ps + 1 < npass) ? ((m0 + 32) >> 5) : (m0 >> 5);
    uint32_t bd_nxt = brow[nwidx];
    {
      const char* ksrc = xb + (long long)m0*512;
      #pragma unroll
      for (int i = 0; i < 4; ++i)
        gl_lds16(ksrc + koff[i], Ks + wv*4096 + i*1024);
      const char* hsrc = hb + m0*2;
      const char* lsrc = lb + m0*2;
      #pragma unroll
      for (int i = 0; i < 5; ++i) {
        gl_lds16(hsrc + hoff[i], Hh + wv*5120 + i*1024);
        gl_lds16(lsrc + hoff[i], Hl + wv*5120 + i*1024);
      }
    }
    __syncthreads();

    // S^T = K * Q^T  (fp16 MFMA; C: col=n=lane&31, row=m=(r&3)+8*(r>>2)+4*hi)
    f32x16 s = {};
    __builtin_amdgcn_s_setprio(1);
    #pragma unroll
    for (int ks = 0; ks < 16; ++ks) {
      int slot = (ks*2 + hi) ^ (ln31 & 7);
      u32x4 a = *(const u32x4*)(Ks + ln31*512 + slot*16);
      asm("v_mfma_f32_32x32x16_f16 %0, %1, %2, %0" : "+v"(s) : "v"(a), "v"(q[ks]));
    }
    __builtin_amdgcn_s_setprio(0);
    asm volatile("s_nop 7\n\ts_nop 7\n\ts_nop 7");
    __builtin_amdgcn_sched_barrier(0);

    const uint32_t bd2 = bd_cur >> (hi*4);
    #pragma unroll
    for (int s2 = 0; s2 < 2; ++s2) {
      uint32_t ph[4], pl[4];
      #pragma unroll
      for (int rp = 0; rp < 4; ++rp) {
        uint32_t hw[2], lw[2];
        #pragma unroll
        for (int e = 0; e < 2; ++e) {
          const int r = s2*8 + rp*2 + e;
          float sv = s[r] * 0.09016844005556021f;  // log2(e)/16
          float ex = __builtin_amdgcn_exp2f(sv);
          const int sh = (r & 3) + ((r >> 2) << 3);
          ex = ((bd2 >> sh) & 1u) ? ex : 0.0f;
          den += ex;
          uint32_t t = __float_as_uint(ex) + 0x8000u;
          hw[e] = t >> 16;
          float hf = __uint_as_float(t & 0xFFFF0000u);
          uint32_t t2 = __float_as_uint(ex - hf) + 0x8000u;
          lw[e] = t2 >> 16;
        }
        ph[rp] = hw[0] | (hw[1] << 16);
        pl[rp] = lw[0] | (lw[1] << 16);
      }
      u32x4 pah = { ph[0], ph[1], ph[2], ph[3] };
      u32x4 pal = { pl[0], pl[1], pl[2], pl[3] };
      __builtin_amdgcn_s_setprio(1);
      #pragma unroll
      for (int ot = 0; ot < 8; ++ot) {
        const int ha = (ot*32 + ln31)*80 + s2*32 + hi*16;
        u32x4 vh = *(const u32x4*)(Hh + ha);
        u32x4 vl = *(const u32x4*)(Hl + ha);
        asm("v_mfma_f32_32x32x16_bf16 %0, %1, %2, %0" : "+v"(acc[ot]) : "v"(pah), "v"(vh));
        asm("v_mfma_f32_32x32x16_bf16 %0, %1, %2, %0" : "+v"(acc[ot]) : "v"(pal), "v"(vh));
        asm("v_mfma_f32_32x32x16_bf16 %0, %1, %2, %0" : "+v"(acc[ot]) : "v"(pah), "v"(vl));
      }
      __builtin_amdgcn_s_setprio(0);
    }
    bd_cur = bd_nxt;
    __syncthreads();
  }

  asm volatile("s_nop 7\n\ts_nop 7\n\ts_nop 7");
  __builtin_amdgcn_sched_barrier(0);
  den += __shfl_xor(den, 32);

  if (MS > 1) {
    float* wa = wacc + (((long long)ms*8 + b)*NN + nw)*256;
    #pragma unroll
    for (int ot = 0; ot < 8; ++ot) {
      #pragma unroll
      for (int r = 0; r < 16; ++r) {
        const int n = (r & 3) + 8*(r >> 2) + 4*hi;
        wa[n*256 + ot*32 + ln31] = acc[ot][r];
      }
    }
    if (lane < 32)
      wden[((long long)ms*8 + b)*NN + nw + ln31] = den;
  } else {
    if (lane < 32) dls[wv][ln31] = den;
    __syncthreads();
    #pragma unroll
    for (int ot = 0; ot < 8; ++ot) {
      const float bi = bias[ot*32 + ln31];
      #pragma unroll
      for (int r = 0; r < 16; ++r) {
        const int n = (r & 3) + 8*(r >> 2) + 4*hi;
        const float dn = dls[wv][n] + 1e-10f;
        float v = acc[ot][r] / dn + bi;
        out[((long long)(b*NN + nw + n))*256 + ot*32 + ln31] = (v > 0.0f) ? v : 0.01f*v;
      }
    }
  }
}

// ---------------- combine partials ----------------
template<int MS>
__global__ __launch_bounds__(256) void k_combine(
    const float* __restrict__ wacc, const float* __restrict__ wden,
    const float* __restrict__ bias, float* __restrict__ out)
{
  const int PLANE = 1048576;  // float4 per ms plane
  for (int t = blockIdx.x*256 + threadIdx.x; t < PLANE; t += 2048*256) {
    int row = t >> 6;
    int o4  = t & 63;
    float4 a = ((const float4*)wacc)[t];
    float d = wden[row];
    #pragma unroll
    for (int m = 1; m < MS; ++m) {
      float4 p = ((const float4*)wacc)[t + m*PLANE];
      a.x += p.x; a.y += p.y; a.z += p.z; a.w += p.w;
      d += wden[row + m*16384];
    }
    d += 1e-10f;
    float id = 1.0f / d;
    float4 bi = ((const float4*)bias)[o4];
    float4 r;
    float vx = a.x*id + bi.x; r.x = vx > 0.0f ? vx : 0.01f*vx;
    float vy = a.y*id + bi.y; r.y = vy > 0.0f ? vy : 0.01f*vy;
    float vz = a.z*id + bi.z; r.z = vz > 0.0f ? vz : 0.01f*vz;
    float vw = a.w*id + bi.w; r.w = vw > 0.0f ? vw : 0.01f*vw;
    ((float4*)out)[t] = r;
  }
}

// ---------------- host ----------------
extern "C" void kernel_launch(void* const* d_in, const int* in_sizes, int n_in,
                              void* d_out, int out_size, void* d_ws, size_t ws_size,
                              hipStream_t stream)
{
  const float* inp = (const float*)d_in[0];
  const float* adj = (const float*)d_in[1];
  const float* W   = (const float*)d_in[2];
  const float* bia = (const float*)d_in[3];
  float* out = (float*)d_out;
  char* ws = (char*)d_ws;

  _Float16* xh  = (_Float16*)(ws);                 // 8 MB fp16 x
  uint16_t* HTh = (uint16_t*)(ws + 8388608);       // 8 MB H^T hi
  uint16_t* HTl = (uint16_t*)(ws + 16777216);      // 8 MB H^T lo
  _Float16* wth = (_Float16*)(ws + 25165824);      // 128 KB W^T hi
  _Float16* wtl = (_Float16*)(ws + 25296896);      // 128 KB W^T lo
  uint32_t* bt  = (uint32_t*)(ws + 25427968);      // 4 MB adj bits
  float* den    = (float*)(ws + 29622272);         // 256 KB denom partials
  float* acc    = (float*)(ws + 29884416);         // up to 64 MB acc partials
  const size_t NEED4 = 96993280;
  const size_t NEED2 = 63438848;

  k_prep<<<dim3(6464), dim3(256), 0, stream>>>(adj, inp, W, xh, wth, wtl, bt);
  k_hgemm<<<dim3(256), dim3(256), 0, stream>>>(inp, wth, wtl, HTh, HTl);
  if (ws_size >= NEED4) {
    k_attn<4><<<dim3(512), dim3(256), 0, stream>>>(xh, HTh, HTl, bt, den, acc, nullptr, nullptr);
    k_combine<4><<<dim3(2048), dim3(256), 0, stream>>>(acc, den, bia, out);
  } else if (ws_size >= NEED2) {
    k_attn<2><<<dim3(256), dim3(256), 0, stream>>>(xh, HTh, HTl, bt, den, acc, nullptr, nullptr);
    k_combine<2><<<dim3(2048), dim3(256), 0, stream>>>(acc, den, bia, out);
  } else {
    k_attn<1><<<dim3(128), dim3(256), 0, stream>>>(xh, HTh, HTl, bt, nullptr, nullptr, bia, out);
  }
}